// Round 10
// baseline (121.913 us; speedup 1.0000x reference)
//
#include <hip/hip_runtime.h>

// DirDist_P2P: fused jittered-query construction + exact 5-NN against two
// 2048-point clouds + inverse-distance UDF/grad + weighted scalar loss.
//
// R10: single fused compute kernel. Blocks of 4 waves pair the two clouds:
//   even blocks (group): 2 tgt-centers x 2 clouds; per wave: pass1 center
//     scan -> r5 upper bound; pass2 ballot+mbcnt compaction of accepted
//     points (x,y,z,idxbits) into a per-wave LDS buffer; sentinel-padded
//     fixed-stride drain (INSERT_PAIR of two independent ds_read_b128);
//     xor16/32 merges; per-query exact epilogue.
//   odd blocks (tail): 2 src-queries x 2 clouds; dense per-lane top-5 +
//     6-round butterfly merge (no LDS buffer use).
// All waves write (udf,g) to a separate 1KB LDS exchange; wave 0 computes
// the block's loss terms and does ONE atomicAdd per block; last block (cnt)
// writes out = acc/QTOT. 2 dispatches total (8B memset + main).
// LDS 19.5KB + launch_bounds(256,8) -> 8 blocks/CU: all 2048 blocks
// resident in one shot. Harness ws poison (~40us, 268MB fill) is a fixed
// floor outside kernel control.

#define NPTS   2048
#define UPR    10
#define KNN    5
#define NTGTQ  (NPTS * UPR)           // 20480
#define QTOT   (NTGTQ + NPTS)         // 22528
#define BLOCK  256
#define CAP    288                    // accepted-point buffer per wave (float4)
#define TOTB   2048                   // 1024 group + 1024 tail, parity-interleaved

static __device__ __forceinline__ unsigned umin32(unsigned a, unsigned b) { return a < b ? a : b; }
static __device__ __forceinline__ unsigned umax32(unsigned a, unsigned b) { return a < b ? b : a; }

// pair insert (presort + merge-path), 14 min/max
#define INSERT_PAIR(A0, A1, A2, A3, A4, P, Q)                                  \
    do {                                                                       \
        unsigned _u = umin32(P, Q), _v = umax32(P, Q);                         \
        unsigned _m0u = umax32(A0, _u), _m1u = umax32(A1, _u);                 \
        unsigned _m2u = umax32(A2, _u), _m3u = umax32(A3, _u);                 \
        unsigned _m0v = umax32(A0, _v), _m1v = umax32(A1, _v);                 \
        unsigned _m2v = umax32(A2, _v);                                        \
        A0 = umin32(A0, _u);                                                   \
        A1 = umin32(umin32(A1, _v), _m0u);                                     \
        A2 = umin32(umin32(A2, _m1u), _m0v);                                   \
        A3 = umin32(umin32(A3, _m2u), _m1v);                                   \
        A4 = umin32(umin32(A4, _m3u), _m2v);                                   \
    } while (0)

// 5+5 sorted merge (merge-path), u32 keys
#define MERGE5(a0, a1, a2, a3, a4, c0, c1, c2, c3, c4)                         \
    do {                                                                       \
        unsigned _n0 = umin32(a0, c0);                                         \
        unsigned _n1 = umin32(umin32(a1, c1), umax32(a0, c0));                 \
        unsigned _n2 = umin32(umin32(a2, c2),                                  \
                       umin32(umax32(a1, c0), umax32(a0, c1)));                \
        unsigned _n3 = umin32(umin32(a3, c3),                                  \
                       umin32(umax32(a2, c0),                                  \
                       umin32(umax32(a1, c1), umax32(a0, c2))));               \
        unsigned _n4 = umin32(umin32(a4, c4),                                  \
                       umin32(umax32(a3, c0),                                  \
                       umin32(umax32(a2, c1),                                  \
                       umin32(umax32(a1, c2), umax32(a0, c3)))));              \
        a0 = _n0; a1 = _n1; a2 = _n2; a3 = _n3; a4 = _n4;                      \
    } while (0)

#define SHFL_MERGE(a0, a1, a2, a3, a4, mask)                                   \
    do {                                                                       \
        unsigned _c0 = (unsigned)__shfl_xor((int)a0, mask, 64);                \
        unsigned _c1 = (unsigned)__shfl_xor((int)a1, mask, 64);                \
        unsigned _c2 = (unsigned)__shfl_xor((int)a2, mask, 64);                \
        unsigned _c3 = (unsigned)__shfl_xor((int)a3, mask, 64);                \
        unsigned _c4 = (unsigned)__shfl_xor((int)a4, mask, 64);                \
        MERGE5(a0, a1, a2, a3, a4, _c0, _c1, _c2, _c3, _c4);                   \
    } while (0)

// 5+5 sorted merge, f32 keys
#define FMERGE5(a0, a1, a2, a3, a4, c0, c1, c2, c3, c4)                        \
    do {                                                                       \
        float _g0 = fminf(a0, c0);                                             \
        float _g1 = fminf(fminf(a1, c1), fmaxf(a0, c0));                       \
        float _g2 = fminf(fminf(a2, c2),                                       \
                    fminf(fmaxf(a1, c0), fmaxf(a0, c1)));                      \
        float _g3 = fminf(fminf(a3, c3),                                       \
                    fminf(fmaxf(a2, c0),                                       \
                    fminf(fmaxf(a1, c1), fmaxf(a0, c2))));                     \
        float _g4 = fminf(fminf(a4, c4),                                       \
                    fminf(fmaxf(a3, c0),                                       \
                    fminf(fmaxf(a2, c1),                                       \
                    fminf(fmaxf(a1, c2), fmaxf(a0, c3)))));                    \
        a0 = _g0; a1 = _g1; a2 = _g2; a3 = _g3; a4 = _g4;                      \
    } while (0)

// Exact epilogue from 5 packed keys: returns float4(udf, gx, gy, gz).
static __device__ __forceinline__ float4 udf_epilogue(const float* __restrict__ cp,
                                                      unsigned k0, unsigned k1, unsigned k2,
                                                      unsigned k3, unsigned k4,
                                                      float qx, float qy, float qz) {
    unsigned ks[KNN] = { k0, k1, k2, k3, k4 };
    float wsum = 0.f, gx = 0.f, gy = 0.f, gz = 0.f;
#pragma unroll
    for (int i = 0; i < KNN; ++i) {
        unsigned id = ks[i] & 0x7FFu;
        float px = cp[3 * id + 0], py = cp[3 * id + 1], pz = cp[3 * id + 2];
        float dx = qx - px, dy = qy - py, dz = qz - pz;
        float dd = fmaf(dx, dx, fmaf(dy, dy, dz * dz));
        float inv = 1.0f / (dd + 1e-8f);
        wsum += inv;
        gx += dx * inv; gy += dy * inv; gz += dz * inv;
    }
    float rs = 1.0f / wsum;
    gx *= rs; gy *= rs; gz *= rs;
    float ex = gx + 1e-10f, ey = gy + 1e-10f, ez = gz + 1e-10f;
    float udf = sqrtf(fmaf(ex, ex, fmaf(ey, ey, ez * ez)));
    return make_float4(udf, gx, gy, gz);
}

__global__ __launch_bounds__(BLOCK, 8) void main_kernel(const float* __restrict__ src,
                                                        const float* __restrict__ tgt,
                                                        const float* __restrict__ noise,
                                                        float* __restrict__ acc,
                                                        unsigned* __restrict__ cnt,
                                                        float* __restrict__ out) {
    __shared__ float4 buf[4 * CAP];    // 18432 B: per-wave compaction buffers
    __shared__ float4 exch[4][16];     // 1024 B: per-wave (udf,g) exchange

    const int tid = threadIdx.x;
    const int wv = tid >> 6;
    const int lane = tid & 63;
    const int type = blockIdx.x & 1;   // 0 = group, 1 = tail
    const int pidx = blockIdx.x >> 1;  // 0..1023
    float4* buf4 = buf + wv * CAP;
    const float INF = __int_as_float(0x7F800000);

    if (type == 0) {
        // ---------- group: wave = (center m, cloud); m = 2*pidx + (wv>>1) ----------
        const int m = pidx * 2 + (wv >> 1);
        const int cloud = wv & 1;
        const float* cp = cloud ? src : tgt;

        const float cx = tgt[3 * m + 0], cy = tgt[3 * m + 1], cz = tgt[3 * m + 2];
        const int sub = lane >> 4;     // 0..3
        const int qi = lane & 15;      // queries 0..9 valid

        float qx = cx, qy = cy, qz = cz, delta = 0.f;
        if (qi < UPR) {
            int q = m * UPR + qi;
            float nr0 = noise[3 * q + 0], nr1 = noise[3 * q + 1], nr2 = noise[3 * q + 2];
            qx = fmaf(0.05f, nr0, cx);
            qy = fmaf(0.05f, nr1, cy);
            qz = fmaf(0.05f, nr2, cz);
            delta = 0.05f * sqrtf(fmaf(nr0, nr0, fmaf(nr1, nr1, nr2 * nr2)));
        }
        float dmax = delta;
#pragma unroll
        for (int s = 1; s < 64; s <<= 1) dmax = fmaxf(dmax, __shfl_xor(dmax, s, 64));

        // pass 1: per-lane top-2 exact center d2, butterfly -> r5 upper bound
        float f0 = INF, f1 = INF;
#pragma unroll 4
        for (int j = 0; j < NPTS / 64; ++j) {
            int i = j * 64 + lane;
            float px = cp[3 * i + 0], py = cp[3 * i + 1], pz = cp[3 * i + 2];
            float dx = px - cx, dy = py - cy, dz = pz - cz;
            float s = fmaf(dx, dx, fmaf(dy, dy, dz * dz));
            f1 = fminf(f1, fmaxf(f0, s));
            f0 = fminf(f0, s);
        }
        float f2 = INF, f3 = INF, f4 = INF;
#pragma unroll
        for (int s = 1; s < 64; s <<= 1) {
            float h0 = __shfl_xor(f0, s, 64), h1 = __shfl_xor(f1, s, 64),
                  h2 = __shfl_xor(f2, s, 64), h3 = __shfl_xor(f3, s, 64),
                  h4 = __shfl_xor(f4, s, 64);
            FMERGE5(f0, f1, f2, f3, f4, h0, h1, h2, h3, h4);
        }
        float bnd = sqrtf(f4) + 2.f * dmax + 2e-3f;
        float S = fmaf(bnd, bnd, 1e-6f);

        unsigned b0 = ~0u, b1 = ~0u, b2 = ~0u, b3 = ~0u, b4 = ~0u;

        auto drain = [&](unsigned count) {
            if (lane < 8) buf4[count + lane] = make_float4(INF, INF, INF, 0.f);
            unsigned cnt8 = (count + 7u) & ~7u;
            for (unsigned k = sub; k < cnt8; k += 8) {
                float4 P = buf4[k];
                float4 Q = buf4[k + 4];
                float dxp = P.x - qx, dyp = P.y - qy, dzp = P.z - qz;
                float dp = fmaf(dxp, dxp, fmaf(dyp, dyp, dzp * dzp));
                unsigned kP = (__float_as_uint(dp) & 0xFFFFF800u) |
                              (__float_as_uint(P.w) & 0x7FFu);
                float dxq = Q.x - qx, dyq = Q.y - qy, dzq = Q.z - qz;
                float dq = fmaf(dxq, dxq, fmaf(dyq, dyq, dzq * dzq));
                unsigned kQ = (__float_as_uint(dq) & 0xFFFFF800u) |
                              (__float_as_uint(Q.w) & 0x7FFu);
                INSERT_PAIR(b0, b1, b2, b3, b4, kP, kQ);
            }
        };

        // pass 2: rescan + ballot/mbcnt compaction (x,y,z,idxbits)
        unsigned scnt = 0;
        for (int j = 0; j < NPTS / 64; ++j) {
            int i = j * 64 + lane;
            float px = cp[3 * i + 0], py = cp[3 * i + 1], pz = cp[3 * i + 2];
            float dx = px - cx, dy = py - cy, dz = pz - cz;
            float s = fmaf(dx, dx, fmaf(dy, dy, dz * dz));
            bool pred = s <= S;
            unsigned long long mask = __ballot(pred);
            unsigned pre = __builtin_amdgcn_mbcnt_hi((unsigned)(mask >> 32),
                           __builtin_amdgcn_mbcnt_lo((unsigned)mask, 0));
            if (pred) buf4[scnt + pre] = make_float4(px, py, pz, __uint_as_float((unsigned)i));
            scnt += (unsigned)__popcll(mask);
            if (scnt > CAP - 72) { drain(scnt); scnt = 0; }   // overflow (rare), exact
        }
        drain(scnt);

        SHFL_MERGE(b0, b1, b2, b3, b4, 16);
        SHFL_MERGE(b0, b1, b2, b3, b4, 32);

        if (sub == 0 && qi < UPR) {
            exch[wv][qi] = udf_epilogue(cp, b0, b1, b2, b3, b4, qx, qy, qz);
        }
    } else {
        // ---------- tail: wave = (src-query i0, cloud); i0 = 2*pidx + (wv>>1) ----------
        const int i0 = pidx * 2 + (wv >> 1);
        const int cloud = wv & 1;
        const float* cp = cloud ? src : tgt;

        const float qx = src[3 * i0 + 0], qy = src[3 * i0 + 1], qz = src[3 * i0 + 2];

        unsigned b0 = ~0u, b1 = ~0u, b2 = ~0u, b3 = ~0u, b4 = ~0u;
#pragma unroll 4
        for (int j = 0; j < NPTS / 64; j += 2) {
            int i1 = j * 64 + lane;
            int i2 = i1 + 64;
            float p1x = cp[3 * i1 + 0], p1y = cp[3 * i1 + 1], p1z = cp[3 * i1 + 2];
            float p2x = cp[3 * i2 + 0], p2y = cp[3 * i2 + 1], p2z = cp[3 * i2 + 2];
            float dx1 = p1x - qx, dy1 = p1y - qy, dz1 = p1z - qz;
            float d1 = fmaf(dx1, dx1, fmaf(dy1, dy1, dz1 * dz1));
            unsigned k1 = (__float_as_uint(d1) & 0xFFFFF800u) | (unsigned)i1;
            float dx2 = p2x - qx, dy2 = p2y - qy, dz2 = p2z - qz;
            float d2 = fmaf(dx2, dx2, fmaf(dy2, dy2, dz2 * dz2));
            unsigned k2 = (__float_as_uint(d2) & 0xFFFFF800u) | (unsigned)i2;
            INSERT_PAIR(b0, b1, b2, b3, b4, k1, k2);
        }
#pragma unroll
        for (int mask = 1; mask < 64; mask <<= 1) {
            SHFL_MERGE(b0, b1, b2, b3, b4, mask);
        }
        if (lane == 0) {
            exch[wv][0] = udf_epilogue(cp, b0, b1, b2, b3, b4, qx, qy, qz);
        }
    }

    __syncthreads();

    // ---------- wave 0: block loss terms -> one atomicAdd ----------
    if (wv == 0) {
        float contrib = 0.f;
        if (lane < 32) {
            const int c = lane >> 4;      // which pair member (center / query)
            const int qi = lane & 15;
            bool valid = type == 0 ? (qi < UPR) : (qi == 0);
            if (valid) {
                float4 t = exch[2 * c + 0][qi];   // tgt-cloud result
                float4 s = exch[2 * c + 1][qi];   // src-cloud result
                float ue  = fabsf(t.x - s.x);
                float uge = fabsf(s.y - t.y) + fabsf(s.z - t.z) + fabsf(s.w - t.w);
                float sum = ue + uge;
                contrib = sum * expf(-3.0f * sum);
            }
        }
#pragma unroll
        for (int mask = 1; mask < 32; mask <<= 1)
            contrib += __shfl_xor(contrib, mask, 64);

        if (lane == 0) {
            atomicAdd(acc, contrib);
            __threadfence();
            unsigned done = atomicAdd(cnt, 1u);
            if (done == TOTB - 1) {
                float sfin = atomicAdd(acc, 0.0f);
                out[0] = sfin / (float)QTOT;
            }
        }
    }
}

extern "C" void kernel_launch(void* const* d_in, const int* in_sizes, int n_in,
                              void* d_out, int out_size, void* d_ws, size_t ws_size,
                              hipStream_t stream) {
    const float* src   = (const float*)d_in[0];
    const float* tgt   = (const float*)d_in[1];
    const float* noise = (const float*)d_in[2];
    float* out = (float*)d_out;

    float* acc = (float*)d_ws;                 // ws[0]
    unsigned* cnt = (unsigned*)d_ws + 1;       // ws[1]

    hipMemsetAsync(d_ws, 0, 8, stream);
    main_kernel<<<TOTB, BLOCK, 0, stream>>>(src, tgt, noise, acc, cnt, out);
}

// Round 11
// 75.372 us; speedup vs baseline: 1.6175x; 1.6175x over previous
//
#include <hip/hip_runtime.h>

// DirDist_P2P: fused jittered-query construction + exact 5-NN against two
// 2048-point clouds + inverse-distance UDF/grad + weighted scalar loss.
//
// R11 = R9 structure (proven 80us) + float4 scan loads (4 points/lane/step,
// 4x fewer VMEM instructions, identical math/keys/indices).
//   Group path (20480 jittered queries, groups of 10 around tgt centers):
//   pass1 center-scan -> r5 upper bound (per-lane top-2, butterfly merge);
//   pass2 per-slot ballot+mbcnt compaction of accepted points into per-wave
//   LDS (x,y,z,idxbits); sentinel-padded fixed-stride drain; xor16/32 merge.
//   Tail (2048 src queries): one wave per (query,cloud), dense top-5.
// launch_bounds(256,7): no VGPR squeeze (R10's (256,8) regressed 2.3x).
// Harness ws poison (~40us, 268MB fill) is a fixed floor outside control.

#define NPTS   2048
#define UPR    10
#define KNN    5
#define NTGTQ  (NPTS * UPR)           // 20480
#define QTOT   (NTGTQ + NPTS)         // 22528
#define BLOCK  256
#define NGRPB  1024                   // group blocks (4 wave-tasks each)
#define NTAILB 1024                   // tail blocks (4 wave-tasks each)
#define NB_MAIN (NGRPB + NTAILB)      // 2048
#define CAP    320                    // accepted-point buffer per wave (float4)
#define BLOCK2 256
#define NB2    (QTOT / BLOCK2)        // 88

static __device__ __forceinline__ unsigned umin32(unsigned a, unsigned b) { return a < b ? a : b; }
static __device__ __forceinline__ unsigned umax32(unsigned a, unsigned b) { return a < b ? b : a; }

// pair insert (presort + merge-path), 14 min/max
#define INSERT_PAIR(A0, A1, A2, A3, A4, P, Q)                                  \
    do {                                                                       \
        unsigned _u = umin32(P, Q), _v = umax32(P, Q);                         \
        unsigned _m0u = umax32(A0, _u), _m1u = umax32(A1, _u);                 \
        unsigned _m2u = umax32(A2, _u), _m3u = umax32(A3, _u);                 \
        unsigned _m0v = umax32(A0, _v), _m1v = umax32(A1, _v);                 \
        unsigned _m2v = umax32(A2, _v);                                        \
        A0 = umin32(A0, _u);                                                   \
        A1 = umin32(umin32(A1, _v), _m0u);                                     \
        A2 = umin32(umin32(A2, _m1u), _m0v);                                   \
        A3 = umin32(umin32(A3, _m2u), _m1v);                                   \
        A4 = umin32(umin32(A4, _m3u), _m2v);                                   \
    } while (0)

// 5+5 sorted merge (merge-path), u32 keys
#define MERGE5(a0, a1, a2, a3, a4, c0, c1, c2, c3, c4)                         \
    do {                                                                       \
        unsigned _n0 = umin32(a0, c0);                                         \
        unsigned _n1 = umin32(umin32(a1, c1), umax32(a0, c0));                 \
        unsigned _n2 = umin32(umin32(a2, c2),                                  \
                       umin32(umax32(a1, c0), umax32(a0, c1)));                \
        unsigned _n3 = umin32(umin32(a3, c3),                                  \
                       umin32(umax32(a2, c0),                                  \
                       umin32(umax32(a1, c1), umax32(a0, c2))));               \
        unsigned _n4 = umin32(umin32(a4, c4),                                  \
                       umin32(umax32(a3, c0),                                  \
                       umin32(umax32(a2, c1),                                  \
                       umin32(umax32(a1, c2), umax32(a0, c3)))));              \
        a0 = _n0; a1 = _n1; a2 = _n2; a3 = _n3; a4 = _n4;                      \
    } while (0)

#define SHFL_MERGE(a0, a1, a2, a3, a4, mask)                                   \
    do {                                                                       \
        unsigned _c0 = (unsigned)__shfl_xor((int)a0, mask, 64);                \
        unsigned _c1 = (unsigned)__shfl_xor((int)a1, mask, 64);                \
        unsigned _c2 = (unsigned)__shfl_xor((int)a2, mask, 64);                \
        unsigned _c3 = (unsigned)__shfl_xor((int)a3, mask, 64);                \
        unsigned _c4 = (unsigned)__shfl_xor((int)a4, mask, 64);                \
        MERGE5(a0, a1, a2, a3, a4, _c0, _c1, _c2, _c3, _c4);                   \
    } while (0)

// 5+5 sorted merge, f32 keys
#define FMERGE5(a0, a1, a2, a3, a4, c0, c1, c2, c3, c4)                        \
    do {                                                                       \
        float _g0 = fminf(a0, c0);                                             \
        float _g1 = fminf(fminf(a1, c1), fmaxf(a0, c0));                       \
        float _g2 = fminf(fminf(a2, c2),                                       \
                    fminf(fmaxf(a1, c0), fmaxf(a0, c1)));                      \
        float _g3 = fminf(fminf(a3, c3),                                       \
                    fminf(fmaxf(a2, c0),                                       \
                    fminf(fmaxf(a1, c1), fmaxf(a0, c2))));                     \
        float _g4 = fminf(fminf(a4, c4),                                       \
                    fminf(fmaxf(a3, c0),                                       \
                    fminf(fmaxf(a2, c1),                                       \
                    fminf(fmaxf(a1, c2), fmaxf(a0, c3)))));                    \
        a0 = _g0; a1 = _g1; a2 = _g2; a3 = _g3; a4 = _g4;                      \
    } while (0)

__global__ __launch_bounds__(BLOCK, 7) void main_kernel(const float* __restrict__ src,
                                                        const float* __restrict__ tgt,
                                                        const float* __restrict__ noise,
                                                        float4* __restrict__ res) {
    __shared__ float4 buf[4 * CAP];   // 20480 B: per-wave compaction buffers
    const int tid = threadIdx.x;
    const int wv = tid >> 6;
    const int lane = tid & 63;
    float4* buf4 = buf + wv * CAP;
    const float INF = __int_as_float(0x7F800000);

    if (blockIdx.x < NGRPB) {
        // ---------------- group path: one wave per (tgt-center, cloud) ----------------
        const int task = blockIdx.x * 4 + wv;           // 0..4095
        const int m = task >> 1;
        const int cloud = task & 1;
        const float* cp = cloud ? src : tgt;
        const float4* g4 = reinterpret_cast<const float4*>(cp);

        const float cx = tgt[3 * m + 0], cy = tgt[3 * m + 1], cz = tgt[3 * m + 2];

        // lane map: sub = lane>>4 (0..3), qi = lane&15 (queries 0..9 valid)
        const int sub = lane >> 4;
        const int qi = lane & 15;

        float qx = cx, qy = cy, qz = cz, delta = 0.f;
        if (qi < UPR) {
            int q = m * UPR + qi;
            float nr0 = noise[3 * q + 0], nr1 = noise[3 * q + 1], nr2 = noise[3 * q + 2];
            qx = fmaf(0.05f, nr0, cx);
            qy = fmaf(0.05f, nr1, cy);
            qz = fmaf(0.05f, nr2, cz);
            delta = 0.05f * sqrtf(fmaf(nr0, nr0, fmaf(nr1, nr1, nr2 * nr2)));
        }
        float dmax = delta;
#pragma unroll
        for (int s = 1; s < 64; s <<= 1) dmax = fmaxf(dmax, __shfl_xor(dmax, s, 64));

        // pass 1: float4 loads, 4 points/lane/step; per-lane top-2 center d2
        float f0 = INF, f1 = INF;
#pragma unroll 2
        for (int j = 0; j < NPTS / 256; ++j) {
            int t = j * 64 + lane;
            float4 A = g4[3 * t + 0];
            float4 B = g4[3 * t + 1];
            float4 C = g4[3 * t + 2];
            float dx, dy, dz, s;
            dx = A.x - cx; dy = A.y - cy; dz = A.z - cz;
            s = fmaf(dx, dx, fmaf(dy, dy, dz * dz));
            f1 = fminf(f1, fmaxf(f0, s)); f0 = fminf(f0, s);
            dx = A.w - cx; dy = B.x - cy; dz = B.y - cz;
            s = fmaf(dx, dx, fmaf(dy, dy, dz * dz));
            f1 = fminf(f1, fmaxf(f0, s)); f0 = fminf(f0, s);
            dx = B.z - cx; dy = B.w - cy; dz = C.x - cz;
            s = fmaf(dx, dx, fmaf(dy, dy, dz * dz));
            f1 = fminf(f1, fmaxf(f0, s)); f0 = fminf(f0, s);
            dx = C.y - cx; dy = C.z - cy; dz = C.w - cz;
            s = fmaf(dx, dx, fmaf(dy, dy, dz * dz));
            f1 = fminf(f1, fmaxf(f0, s)); f0 = fminf(f0, s);
        }
        float f2 = INF, f3 = INF, f4 = INF;
#pragma unroll
        for (int s = 1; s < 64; s <<= 1) {
            float h0 = __shfl_xor(f0, s, 64), h1 = __shfl_xor(f1, s, 64),
                  h2 = __shfl_xor(f2, s, 64), h3 = __shfl_xor(f3, s, 64),
                  h4 = __shfl_xor(f4, s, 64);
            FMERGE5(f0, f1, f2, f3, f4, h0, h1, h2, h3, h4);
        }
        // accept radius: r5ub + 2*dmax with fp slack (d2 exact >= 0)
        float bnd = sqrtf(f4) + 2.f * dmax + 2e-3f;
        float S = fmaf(bnd, bnd, 1e-6f);

        unsigned b0 = ~0u, b1 = ~0u, b2 = ~0u, b3 = ~0u, b4 = ~0u;

        auto drain = [&](unsigned count) {
            // pad to multiple of 8 with inf-sentinels (never win)
            if (lane < 8) buf4[count + lane] = make_float4(INF, INF, INF, 0.f);
            unsigned cnt8 = (count + 7u) & ~7u;
            for (unsigned k = sub; k < cnt8; k += 8) {
                float4 P = buf4[k];
                float4 Q = buf4[k + 4];
                float dxp = P.x - qx, dyp = P.y - qy, dzp = P.z - qz;
                float dp = fmaf(dxp, dxp, fmaf(dyp, dyp, dzp * dzp));
                unsigned kP = (__float_as_uint(dp) & 0xFFFFF800u) |
                              (__float_as_uint(P.w) & 0x7FFu);
                float dxq = Q.x - qx, dyq = Q.y - qy, dzq = Q.z - qz;
                float dq = fmaf(dxq, dxq, fmaf(dyq, dyq, dzq * dzq));
                unsigned kQ = (__float_as_uint(dq) & 0xFFFFF800u) |
                              (__float_as_uint(Q.w) & 0x7FFu);
                INSERT_PAIR(b0, b1, b2, b3, b4, kP, kQ);
            }
        };

        // pass 2: float4 rescan + per-slot ballot/mbcnt compaction
        unsigned scnt = 0;
        for (int j = 0; j < NPTS / 256; ++j) {
            int t = j * 64 + lane;
            float4 A = g4[3 * t + 0];
            float4 B = g4[3 * t + 1];
            float4 C = g4[3 * t + 2];
            float px[4] = { A.x, A.w, B.z, C.y };
            float py[4] = { A.y, B.x, B.w, C.z };
            float pz[4] = { A.z, B.y, C.x, C.w };
#pragma unroll
            for (int sl = 0; sl < 4; ++sl) {
                float dx = px[sl] - cx, dy = py[sl] - cy, dz = pz[sl] - cz;
                float s = fmaf(dx, dx, fmaf(dy, dy, dz * dz));
                bool pred = s <= S;
                unsigned long long mask = __ballot(pred);
                unsigned pre = __builtin_amdgcn_mbcnt_hi((unsigned)(mask >> 32),
                               __builtin_amdgcn_mbcnt_lo((unsigned)mask, 0));
                if (pred)
                    buf4[scnt + pre] = make_float4(px[sl], py[sl], pz[sl],
                                                   __uint_as_float((unsigned)(4 * t + sl)));
                scnt += (unsigned)__popcll(mask);
                if (scnt > CAP - 72) { drain(scnt); scnt = 0; }   // overflow (rare), exact
            }
        }
        drain(scnt);

        // reunify the 4 subs (xor 16, 32)
        SHFL_MERGE(b0, b1, b2, b3, b4, 16);
        SHFL_MERGE(b0, b1, b2, b3, b4, 32);

        if (sub == 0 && qi < UPR) {
            unsigned ks[KNN] = { b0, b1, b2, b3, b4 };
            float wsum = 0.f, gx = 0.f, gy = 0.f, gz = 0.f;
#pragma unroll
            for (int i = 0; i < KNN; ++i) {
                unsigned id = ks[i] & 0x7FFu;
                float px2 = cp[3 * id + 0], py2 = cp[3 * id + 1], pz2 = cp[3 * id + 2];
                float dx = qx - px2, dy = qy - py2, dz = qz - pz2;
                float dd = fmaf(dx, dx, fmaf(dy, dy, dz * dz));
                float inv = 1.0f / (dd + 1e-8f);
                wsum += inv;
                gx += dx * inv; gy += dy * inv; gz += dz * inv;
            }
            float rs = 1.0f / wsum;
            gx *= rs; gy *= rs; gz *= rs;
            float ex = gx + 1e-10f, ey = gy + 1e-10f, ez = gz + 1e-10f;
            float udf = sqrtf(fmaf(ex, ex, fmaf(ey, ey, ez * ez)));
            res[cloud * QTOT + m * UPR + qi] = make_float4(udf, gx, gy, gz);
        }
        return;
    }

    // ---------------- tail path: one wave per (src-query, cloud), float4 scan ----------------
    const int ti = (blockIdx.x - NGRPB) * 4 + wv;       // 0..4095
    const int i0 = ti >> 1;                             // src point index
    const int cloud = ti & 1;
    const float* cp = cloud ? src : tgt;
    const float4* g4 = reinterpret_cast<const float4*>(cp);

    const float qx = src[3 * i0 + 0], qy = src[3 * i0 + 1], qz = src[3 * i0 + 2];

    unsigned b0 = ~0u, b1 = ~0u, b2 = ~0u, b3 = ~0u, b4 = ~0u;
#pragma unroll 2
    for (int j = 0; j < NPTS / 256; ++j) {
        int t = j * 64 + lane;
        float4 A = g4[3 * t + 0];
        float4 B = g4[3 * t + 1];
        float4 C = g4[3 * t + 2];
        unsigned ib = (unsigned)(4 * t);
        float dx, dy, dz, d;
        unsigned k0, k1, k2, k3;
        dx = A.x - qx; dy = A.y - qy; dz = A.z - qz;
        d = fmaf(dx, dx, fmaf(dy, dy, dz * dz));
        k0 = (__float_as_uint(d) & 0xFFFFF800u) | (ib + 0);
        dx = A.w - qx; dy = B.x - qy; dz = B.y - qz;
        d = fmaf(dx, dx, fmaf(dy, dy, dz * dz));
        k1 = (__float_as_uint(d) & 0xFFFFF800u) | (ib + 1);
        dx = B.z - qx; dy = B.w - qy; dz = C.x - qz;
        d = fmaf(dx, dx, fmaf(dy, dy, dz * dz));
        k2 = (__float_as_uint(d) & 0xFFFFF800u) | (ib + 2);
        dx = C.y - qx; dy = C.z - qy; dz = C.w - qz;
        d = fmaf(dx, dx, fmaf(dy, dy, dz * dz));
        k3 = (__float_as_uint(d) & 0xFFFFF800u) | (ib + 3);
        INSERT_PAIR(b0, b1, b2, b3, b4, k0, k1);
        INSERT_PAIR(b0, b1, b2, b3, b4, k2, k3);
    }

#pragma unroll
    for (int mask = 1; mask < 64; mask <<= 1) {
        SHFL_MERGE(b0, b1, b2, b3, b4, mask);
    }

    // all lanes hold the identical final list; lane 0 computes + writes
    if (lane == 0) {
        unsigned ks[KNN] = { b0, b1, b2, b3, b4 };
        float wsum = 0.f, gx = 0.f, gy = 0.f, gz = 0.f;
#pragma unroll
        for (int i = 0; i < KNN; ++i) {
            unsigned id = ks[i] & 0x7FFu;
            float px = cp[3 * id + 0], py = cp[3 * id + 1], pz = cp[3 * id + 2];
            float dx = qx - px, dy = qy - py, dz = qz - pz;
            float dd = fmaf(dx, dx, fmaf(dy, dy, dz * dz));
            float inv = 1.0f / (dd + 1e-8f);
            wsum += inv;
            gx += dx * inv; gy += dy * inv; gz += dz * inv;
        }
        float rs = 1.0f / wsum;
        gx *= rs; gy *= rs; gz *= rs;
        float ex = gx + 1e-10f, ey = gy + 1e-10f, ez = gz + 1e-10f;
        float udf = sqrtf(fmaf(ex, ex, fmaf(ey, ey, ez * ez)));
        res[cloud * QTOT + NTGTQ + i0] = make_float4(udf, gx, gy, gz);
    }
}

__global__ __launch_bounds__(BLOCK2) void loss_kernel(const float4* __restrict__ res,
                                                      float* __restrict__ acc,
                                                      unsigned* __restrict__ cnt,
                                                      float* __restrict__ out) {
    const int q = blockIdx.x * BLOCK2 + threadIdx.x;
    float4 t = res[q];
    float4 s = res[QTOT + q];
    float ue  = fabsf(t.x - s.x);
    float uge = fabsf(s.y - t.y) + fabsf(s.z - t.z) + fabsf(s.w - t.w);
    float sum = ue + uge;
    float term = sum * expf(-3.0f * sum);

#pragma unroll
    for (int m = 1; m < 64; m <<= 1) term += __shfl_xor(term, m, 64);
    __shared__ float red[BLOCK2 / 64];
    if ((threadIdx.x & 63) == 0) red[threadIdx.x >> 6] = term;
    __syncthreads();

    if (threadIdx.x == 0) {
        float partial = 0.f;
#pragma unroll
        for (int w = 0; w < BLOCK2 / 64; ++w) partial += red[w];
        atomicAdd(acc, partial);
        __threadfence();
        unsigned done = atomicAdd(cnt, 1u);
        if (done == NB2 - 1) {
            float sfin = atomicAdd(acc, 0.0f);
            out[0] = sfin / (float)QTOT;
        }
    }
}

extern "C" void kernel_launch(void* const* d_in, const int* in_sizes, int n_in,
                              void* d_out, int out_size, void* d_ws, size_t ws_size,
                              hipStream_t stream) {
    const float* src   = (const float*)d_in[0];
    const float* tgt   = (const float*)d_in[1];
    const float* noise = (const float*)d_in[2];
    float* out = (float*)d_out;

    float* acc = (float*)d_ws;                                 // ws[0]
    unsigned* cnt = (unsigned*)d_ws + 1;                       // ws[1]
    float4* res = (float4*)((char*)d_ws + 16);                 // 2*QTOT float4

    hipMemsetAsync(d_ws, 0, 8, stream);
    main_kernel<<<NB_MAIN, BLOCK, 0, stream>>>(src, tgt, noise, res);
    loss_kernel<<<NB2, BLOCK2, 0, stream>>>(res, acc, cnt, out);
}